// Round 4
// baseline (881.088 us; speedup 1.0000x reference)
//
#include <hip/hip_runtime.h>
#include <hip/hip_fp16.h>
#include <math.h>

#define NB 16
#define L 1024
#define D 256
#define N_ITER 50
#define QSCALE 2560.0f
#define QSC (1.0f/2560.0f)              // q -> distance units
#define LOG2E 1.4426950408889634f
#define QS2 (LOG2E/256.0f)              // q -> log2 units (10*(a-C)*log2e)
#define LOG_MU2 (-10.0f)                // log2(1/1024)
#define TEN_LOG2E 14.426950408889634f

typedef short short4_t __attribute__((ext_vector_type(4)));

// ---------------- norms: x2[row] = sum_k x[row,k]^2 -----------------
__global__ __launch_bounds__(256) void norms_kernel(
    const float* __restrict__ x, const float* __restrict__ y,
    float* __restrict__ x2, float* __restrict__ y2) {
  int wid = threadIdx.x >> 6, lane = threadIdx.x & 63;
  int row = blockIdx.x * 4 + wid;
  const float* src = (row < NB * L) ? (x + (size_t)row * D)
                                    : (y + (size_t)(row - NB * L) * D);
  float4 v = *(const float4*)(src + lane * 4);
  float s = v.x * v.x + v.y * v.y + v.z * v.z + v.w * v.w;
  #pragma unroll
  for (int off = 32; off; off >>= 1) s += __shfl_down(s, off);
  if (lane == 0) {
    if (row < NB * L) x2[row] = s;
    else              y2[row - NB * L] = s;
  }
}

// ------------- anchor[i] = min over 16 sampled cols of C[i,j] -------------
__global__ __launch_bounds__(256) void anchor_kernel(
    const float* __restrict__ x, const float* __restrict__ y,
    const float* __restrict__ x2, const float* __restrict__ y2,
    float* __restrict__ anchor, float* __restrict__ A2) {
  int w = threadIdx.x >> 6, lane = threadIdx.x & 63;
  int gr = blockIdx.x * 4 + w;           // 0..NB*L-1
  int b = gr >> 10, i = gr & 1023;
  const float* xr = x + (size_t)gr * D;
  float4 xv = *(const float4*)(xr + lane * 4);
  float dots[16];
  #pragma unroll
  for (int s = 0; s < 16; ++s) {
    int j = (i + s * 64 + s * s) & 1023;
    float4 yv = *(const float4*)(y + ((size_t)b * L + j) * D + lane * 4);
    dots[s] = xv.x * yv.x + xv.y * yv.y + xv.z * yv.z + xv.w * yv.w;
  }
  #pragma unroll
  for (int s = 0; s < 16; ++s)
    #pragma unroll
    for (int off = 32; off; off >>= 1) dots[s] += __shfl_xor(dots[s], off);
  if (lane == 0) {
    float xx = x2[gr];
    float mn = 3.4e38f;
    #pragma unroll
    for (int s = 0; s < 16; ++s) {
      int j = (i + s * 64 + s * s) & 1023;
      float d2 = xx + y2[b * L + j] - 2.0f * dots[s];
      mn = fminf(mn, sqrtf(fmaxf(d2, 0.0f)));
    }
    anchor[gr] = mn;
    A2[gr] = mn * TEN_LOG2E;
  }
}

// ---------------- single GEMM: Q[i][j] = half((anchor_i - C_ij)*2560) ----
__global__ __launch_bounds__(256) void costq_kernel(
    const float* __restrict__ x, const float* __restrict__ y,
    const float* __restrict__ x2, const float* __restrict__ y2,
    const float* __restrict__ anchor, __half* __restrict__ Q) {
  __shared__ float xs[16][68];
  __shared__ float ys[16][68];
  int bid = blockIdx.x;
  int b = bid >> 8;
  int rem = bid & 255;
  int i0 = (rem >> 4) << 6;
  int j0 = (rem & 15) << 6;
  int tid = threadIdx.x;
  int tx = tid & 15, ty = tid >> 4;
  int r = tid >> 2, kq = tid & 3;

  float acc[4][4] = {};
  const float* xbase = x + ((size_t)b * L + i0 + r) * D + kq * 4;
  const float* ybase = y + ((size_t)b * L + j0 + r) * D + kq * 4;
  float4 xv = *(const float4*)(xbase);
  float4 yv = *(const float4*)(ybase);
  for (int k0 = 0; k0 < D; k0 += 16) {
    int kn = (k0 + 16) & 255;            // harmless wrap refetch on last iter
    float4 nx = *(const float4*)(xbase + kn);
    float4 ny = *(const float4*)(ybase + kn);
    __syncthreads();
    xs[kq * 4 + 0][r] = xv.x; xs[kq * 4 + 1][r] = xv.y;
    xs[kq * 4 + 2][r] = xv.z; xs[kq * 4 + 3][r] = xv.w;
    ys[kq * 4 + 0][r] = yv.x; ys[kq * 4 + 1][r] = yv.y;
    ys[kq * 4 + 2][r] = yv.z; ys[kq * 4 + 3][r] = yv.w;
    __syncthreads();
    #pragma unroll
    for (int kk = 0; kk < 16; ++kk) {
      float4 av = *(const float4*)&xs[kk][ty * 4];
      float4 bv = *(const float4*)&ys[kk][tx * 4];
      float a[4] = {av.x, av.y, av.z, av.w};
      float bb[4] = {bv.x, bv.y, bv.z, bv.w};
      #pragma unroll
      for (int er = 0; er < 4; ++er)
        #pragma unroll
        for (int ec = 0; ec < 4; ++ec)
          acc[er][ec] = fmaf(a[er], bb[ec], acc[er][ec]);
    }
    xv = nx; yv = ny;
  }
  float xr[4], yc[4], ar[4];
  #pragma unroll
  for (int e = 0; e < 4; ++e) {
    xr[e] = x2[b * L + i0 + ty * 4 + e];
    yc[e] = y2[b * L + j0 + tx * 4 + e];
    ar[e] = anchor[b * L + i0 + ty * 4 + e];
  }
  #pragma unroll
  for (int er = 0; er < 4; ++er) {
    short4_t q4;
    #pragma unroll
    for (int ec = 0; ec < 4; ++ec) {
      float d2 = xr[er] + yc[ec] - 2.0f * acc[er][ec];
      float c = sqrtf(fmaxf(d2, 0.0f));
      float qv = fminf(fmaxf((ar[er] - c) * QSCALE, -30000.0f), 30000.0f);
      __half h = __float2half(qv);
      q4[ec] = __half_as_short(h);
    }
    *(short4_t*)((short*)Q + ((size_t)b * L + i0 + ty * 4 + er) * L + j0 + tx * 4) = q4;
  }
}

#define DEC2(word, base)                                           \
  { __half2 h2 = *reinterpret_cast<const __half2*>(&(word));       \
    float2 f2 = __half22float2(h2);                                \
    t[base]     = exp2f(fmaf(f2.x, QS2, vv[base]));                \
    t[base + 1] = exp2f(fmaf(f2.y, QS2, vv[base + 1])); }

// ---- fused pass: row-LSE -> u2; shifted col partials for v-update --------
__global__ __launch_bounds__(256) void pass_fused_kernel(
    const __half* __restrict__ Q, const float* __restrict__ A2,
    const float* __restrict__ v2, const float* __restrict__ bmax,
    float* __restrict__ u2out, float* __restrict__ partial) {
  __shared__ float4 cacc[4][256];
  int bb = blockIdx.x;                 // NB*64 blocks, 16 rows each
  int tid = threadIdx.x;
  int w = tid >> 6, lane = tid & 63;
  int b = bb >> 6;
  int r0 = bb * 16 + w;                // this wave's rows: r0, +4, +8, +12

  // prefetch all Q data first (8 x 16B per lane)
  const int4* q0 = (const int4*)(Q + (size_t)r0 * L);
  const int4* q1 = (const int4*)(Q + (size_t)(r0 + 4) * L);
  const int4* q2 = (const int4*)(Q + (size_t)(r0 + 8) * L);
  const int4* q3 = (const int4*)(Q + (size_t)(r0 + 12) * L);
  int4 cA0 = q0[lane], cB0 = q0[64 + lane];
  int4 cA1 = q1[lane], cB1 = q1[64 + lane];
  int4 cA2 = q2[lane], cB2 = q2[64 + lane];
  int4 cA3 = q3[lane], cB3 = q3[64 + lane];

  const float* bm = bmax + b * 16;
  float m2 = bm[0];
  #pragma unroll
  for (int k = 1; k < 16; ++k) m2 = fmaxf(m2, bm[k]);

  const float4* g4 = (const float4*)(v2 + (b << 10));
  float4 a0 = g4[lane * 2], a1 = g4[lane * 2 + 1];
  float4 a2 = g4[128 + lane * 2], a3 = g4[128 + lane * 2 + 1];
  float vv[16];
  vv[0]=a0.x-m2; vv[1]=a0.y-m2; vv[2]=a0.z-m2; vv[3]=a0.w-m2;
  vv[4]=a1.x-m2; vv[5]=a1.y-m2; vv[6]=a1.z-m2; vv[7]=a1.w-m2;
  vv[8]=a2.x-m2; vv[9]=a2.y-m2; vv[10]=a2.z-m2; vv[11]=a2.w-m2;
  vv[12]=a3.x-m2; vv[13]=a3.y-m2; vv[14]=a3.z-m2; vv[15]=a3.w-m2;
  float E2 = exp2f(LOG_MU2 - m2);
  float colacc[16] = {};
  float r_0, r_1, r_2, r_3;

#define ROWP(cA_, cB_, ROUT)                                              \
  { float t[16];                                                          \
    DEC2(cA_.x, 0) DEC2(cA_.y, 2) DEC2(cA_.z, 4) DEC2(cA_.w, 6)           \
    DEC2(cB_.x, 8) DEC2(cB_.y, 10) DEC2(cB_.z, 12) DEC2(cB_.w, 14)        \
    float racc = ((t[0]+t[1])+(t[2]+t[3])) + ((t[4]+t[5])+(t[6]+t[7]))    \
               + ((t[8]+t[9])+(t[10]+t[11])) + ((t[12]+t[13])+(t[14]+t[15])); \
    _Pragma("unroll")                                                     \
    for (int off = 32; off; off >>= 1) racc += __shfl_xor(racc, off);     \
    float g = E2 / racc;                                                  \
    _Pragma("unroll")                                                     \
    for (int k = 0; k < 16; ++k) colacc[k] = fmaf(t[k], g, colacc[k]);    \
    ROUT = racc; }

  ROWP(cA0, cB0, r_0)
  ROWP(cA1, cB1, r_1)
  ROWP(cA2, cB2, r_2)
  ROWP(cA3, cB3, r_3)
#undef ROWP

  if (lane == 0) {
    u2out[r0]      = LOG_MU2 + A2[r0]      - m2 - log2f(r_0);
    u2out[r0 + 4]  = LOG_MU2 + A2[r0 + 4]  - m2 - log2f(r_1);
    u2out[r0 + 8]  = LOG_MU2 + A2[r0 + 8]  - m2 - log2f(r_2);
    u2out[r0 + 12] = LOG_MU2 + A2[r0 + 12] - m2 - log2f(r_3);
  }
  cacc[w][lane * 2]           = {colacc[0], colacc[1], colacc[2], colacc[3]};
  cacc[w][lane * 2 + 1]       = {colacc[4], colacc[5], colacc[6], colacc[7]};
  cacc[w][128 + lane * 2]     = {colacc[8], colacc[9], colacc[10], colacc[11]};
  cacc[w][128 + lane * 2 + 1] = {colacc[12], colacc[13], colacc[14], colacc[15]};
  __syncthreads();
  float4 s0 = cacc[0][tid], s1 = cacc[1][tid], s2 = cacc[2][tid], s3 = cacc[3][tid];
  float4 s = {s0.x + s1.x + s2.x + s3.x, s0.y + s1.y + s2.y + s3.y,
              s0.z + s1.z + s2.z + s3.z, s0.w + s1.w + s2.w + s3.w};
  ((float4*)partial)[bb * 256 + tid] = s;
}

// ------- v2[j] = LOG_NU2 - log2(sum partials) + v2old[j] - m2; bmax_next ---
__global__ __launch_bounds__(256) void reducev_kernel(
    const float* __restrict__ partial, float* __restrict__ v2,
    const float* __restrict__ bmax_cur, float* __restrict__ bmax_next) {
  __shared__ float ss[4][64];
  int blk = blockIdx.x;                 // NB*16 blocks, 64 cols each
  int b = blk >> 4;
  int j0 = (blk & 15) << 6;
  int tid = threadIdx.x;
  int c = tid & 63, q = tid >> 6;
  const float* p = partial + (((size_t)b * 64 + q * 16) << 10) + j0 + c;
  float s = 0.0f;
  #pragma unroll
  for (int k = 0; k < 16; ++k) s += p[(size_t)k << 10];
  ss[q][c] = s;
  __syncthreads();
  if (tid < 64) {
    const float* bm = bmax_cur + b * 16;
    float m2 = bm[0];
    #pragma unroll
    for (int k = 1; k < 16; ++k) m2 = fmaxf(m2, bm[k]);
    float S = ss[0][c] + ss[1][c] + ss[2][c] + ss[3][c];
    int j = (b << 10) + j0 + c;
    float vn = LOG_MU2 - log2f(S) + v2[j] - m2;
    v2[j] = vn;
    float mx = vn;
    #pragma unroll
    for (int off = 32; off; off >>= 1) mx = fmaxf(mx, __shfl_xor(mx, off));
    if (c == 0) bmax_next[blk] = mx;
  }
}

// ---------------- distance partials: sum 2^(s2+u2+v2) * C ----------------
__global__ __launch_bounds__(256) void distance_kernel(
    const __half* __restrict__ Q, const float* __restrict__ anchor,
    const float* __restrict__ A2, const float* __restrict__ u2,
    const float* __restrict__ v2, float* __restrict__ pdist) {
  __shared__ float red[4];
  int bb = blockIdx.x;
  int tid = threadIdx.x;
  int w = tid >> 6, lane = tid & 63;
  int b = bb >> 6;
  int r0 = bb * 16 + w;
  const int4* q0 = (const int4*)(Q + (size_t)r0 * L);
  const int4* q1 = (const int4*)(Q + (size_t)(r0 + 4) * L);
  const int4* q2 = (const int4*)(Q + (size_t)(r0 + 8) * L);
  const int4* q3 = (const int4*)(Q + (size_t)(r0 + 12) * L);
  int4 cA0 = q0[lane], cB0 = q0[64 + lane];
  int4 cA1 = q1[lane], cB1 = q1[64 + lane];
  int4 cA2 = q2[lane], cB2 = q2[64 + lane];
  int4 cA3 = q3[lane], cB3 = q3[64 + lane];

  const float4* g4 = (const float4*)(v2 + (b << 10));
  float4 a0 = g4[lane * 2], a1 = g4[lane * 2 + 1];
  float4 a2 = g4[128 + lane * 2], a3 = g4[128 + lane * 2 + 1];
  float vv[16];
  vv[0]=a0.x; vv[1]=a0.y; vv[2]=a0.z; vv[3]=a0.w;
  vv[4]=a1.x; vv[5]=a1.y; vv[6]=a1.z; vv[7]=a1.w;
  vv[8]=a2.x; vv[9]=a2.y; vv[10]=a2.z; vv[11]=a2.w;
  vv[12]=a3.x; vv[13]=a3.y; vv[14]=a3.z; vv[15]=a3.w;

  float racc = 0.0f;
#define DROW(cA_, cB_, ROFF)                                              \
  { int r = r0 + ROFF;                                                    \
    float ar = anchor[r];                                                 \
    float base = u2[r] - A2[r];                                           \
    float va[16];                                                         \
    _Pragma("unroll")                                                     \
    for (int k = 0; k < 16; ++k) va[k] = vv[k] + base;                    \
    float t[16];                                                          \
    { float* vvsave = va; float* vv = vvsave;                             \
      DEC2(cA_.x, 0) DEC2(cA_.y, 2) DEC2(cA_.z, 4) DEC2(cA_.w, 6)         \
      DEC2(cB_.x, 8) DEC2(cB_.y, 10) DEC2(cB_.z, 12) DEC2(cB_.w, 14) }    \
    __half2 h2; float2 f2;                                                \
    h2 = *reinterpret_cast<const __half2*>(&cA_.x); f2 = __half22float2(h2); \
    racc = fmaf(t[0], fmaf(f2.x, -QSC, ar), racc);                        \
    racc = fmaf(t[1], fmaf(f2.y, -QSC, ar), racc);                        \
    h2 = *reinterpret_cast<const __half2*>(&cA_.y); f2 = __half22float2(h2); \
    racc = fmaf(t[2], fmaf(f2.x, -QSC, ar), racc);                        \
    racc = fmaf(t[3], fmaf(f2.y, -QSC, ar), racc);                        \
    h2 = *reinterpret_cast<const __half2*>(&cA_.z); f2 = __half22float2(h2); \
    racc = fmaf(t[4], fmaf(f2.x, -QSC, ar), racc);                        \
    racc = fmaf(t[5], fmaf(f2.y, -QSC, ar), racc);                        \
    h2 = *reinterpret_cast<const __half2*>(&cA_.w); f2 = __half22float2(h2); \
    racc = fmaf(t[6], fmaf(f2.x, -QSC, ar), racc);                        \
    racc = fmaf(t[7], fmaf(f2.y, -QSC, ar), racc);                        \
    h2 = *reinterpret_cast<const __half2*>(&cB_.x); f2 = __half22float2(h2); \
    racc = fmaf(t[8], fmaf(f2.x, -QSC, ar), racc);                        \
    racc = fmaf(t[9], fmaf(f2.y, -QSC, ar), racc);                        \
    h2 = *reinterpret_cast<const __half2*>(&cB_.y); f2 = __half22float2(h2); \
    racc = fmaf(t[10], fmaf(f2.x, -QSC, ar), racc);                       \
    racc = fmaf(t[11], fmaf(f2.y, -QSC, ar), racc);                       \
    h2 = *reinterpret_cast<const __half2*>(&cB_.z); f2 = __half22float2(h2); \
    racc = fmaf(t[12], fmaf(f2.x, -QSC, ar), racc);                       \
    racc = fmaf(t[13], fmaf(f2.y, -QSC, ar), racc);                       \
    h2 = *reinterpret_cast<const __half2*>(&cB_.w); f2 = __half22float2(h2); \
    racc = fmaf(t[14], fmaf(f2.x, -QSC, ar), racc);                       \
    racc = fmaf(t[15], fmaf(f2.y, -QSC, ar), racc); }

  DROW(cA0, cB0, 0)
  DROW(cA1, cB1, 4)
  DROW(cA2, cB2, 8)
  DROW(cA3, cB3, 12)
#undef DROW

  #pragma unroll
  for (int off = 32; off; off >>= 1) racc += __shfl_xor(racc, off);
  if (lane == 0) red[w] = racc;
  __syncthreads();
  if (tid == 0) pdist[bb] = red[0] + red[1] + red[2] + red[3];
}

__global__ __launch_bounds__(256) void finalred_kernel(
    const float* __restrict__ pdist, float* __restrict__ out) {
  __shared__ float red[4];
  int tid = threadIdx.x;
  float s = pdist[tid] + pdist[tid + 256] + pdist[tid + 512] + pdist[tid + 768];
  #pragma unroll
  for (int off = 32; off; off >>= 1) s += __shfl_xor(s, off);
  int w = tid >> 6;
  if ((tid & 63) == 0) red[w] = s;
  __syncthreads();
  if (tid == 0) out[0] = (red[0] + red[1] + red[2] + red[3]) * (1.0f / NB);
}

extern "C" void kernel_launch(void* const* d_in, const int* in_sizes, int n_in,
                              void* d_out, int out_size, void* d_ws, size_t ws_size,
                              hipStream_t stream) {
  const float* x = (const float*)d_in[0];
  const float* y = (const float*)d_in[1];
  float* out = (float*)d_out;
  char* ws = (char*)d_ws;

  const size_t szQ = (size_t)NB * L * L * sizeof(__half);        // 32 MB
  const size_t szP = (size_t)NB * 64 * L * sizeof(float);        // 4 MB
  __half* Q = (__half*)ws;
  float* partial = (float*)(ws + szQ);
  float* x2 = (float*)(ws + szQ + szP);
  float* y2 = x2 + NB * L;
  float* anchor = y2 + NB * L;
  float* A2 = anchor + NB * L;
  float* lu = A2 + NB * L;
  float* lv = lu + NB * L;
  float* bmA = lv + NB * L;
  float* bmB = bmA + 256;
  float* pdist = bmB + 256;

  hipMemsetAsync(lv, 0, NB * L * sizeof(float), stream);         // v2_0 = 0
  hipMemsetAsync(bmA, 0, 256 * sizeof(float), stream);           // max(v2_0) = 0

  norms_kernel<<<2 * NB * L / 4, 256, 0, stream>>>(x, y, x2, y2);
  anchor_kernel<<<NB * L / 4, 256, 0, stream>>>(x, y, x2, y2, anchor, A2);
  costq_kernel<<<NB * 256, 256, 0, stream>>>(x, y, x2, y2, anchor, Q);

  float* bmc = bmA;
  float* bmn = bmB;
  for (int t = 0; t < N_ITER; ++t) {
    pass_fused_kernel<<<NB * 64, 256, 0, stream>>>(Q, A2, lv, bmc, lu, partial);
    reducev_kernel<<<NB * 16, 256, 0, stream>>>(partial, lv, bmc, bmn);
    float* tmp = bmc; bmc = bmn; bmn = tmp;
  }
  distance_kernel<<<NB * 64, 256, 0, stream>>>(Q, anchor, A2, lu, lv, pdist);
  finalred_kernel<<<1, 256, 0, stream>>>(pdist, out);
}